// Round 4
// baseline (268.973 us; speedup 1.0000x reference)
//
#include <hip/hip_runtime.h>
#include <hip/hip_bf16.h>

// Problem constants (B=8, N=256, DIN=DOUT=EIN=EOUT=64)
#define BN   2048      // B*N
#define NN   256       // N
#define CH   64        // channel dims

typedef __attribute__((ext_vector_type(8))) short short8;   // 8 bf16
typedef __attribute__((ext_vector_type(4))) float fv4;

// fp32 -> bf16 bits, round-to-nearest-even
static __device__ inline short f2bf(float f) {
  unsigned u = __float_as_uint(f);
  u += 0x7FFF + ((u >> 16) & 1);
  return (short)(u >> 16);
}
static __device__ inline short8 cvt8(fv4 a, fv4 b) {
  short8 f;
  f[0] = f2bf(a[0]); f[1] = f2bf(a[1]); f[2] = f2bf(a[2]); f[3] = f2bf(a[3]);
  f[4] = f2bf(b[0]); f[5] = f2bf(b[1]); f[6] = f2bf(b[2]); f[7] = f2bf(b[3]);
  return f;
}

// ---------------------------------------------------------------------------
// Kernel 1: node_x = emb_node@Wn + bn (fp32), rsx = relu(emb_node@Wsn + bsn).
// ---------------------------------------------------------------------------
__global__ __launch_bounds__(256) void node_kernel(
    const float* __restrict__ emb_node, const float* __restrict__ Wn,
    const float* __restrict__ bn, const float* __restrict__ Wsn,
    const float* __restrict__ bsn, float* __restrict__ node_x,
    float* __restrict__ rsx) {
  __shared__ float s_emb[4][CH];
  __shared__ float s_Wn[CH * CH];
  __shared__ float s_Ws[CH * CH];
  const int tid = threadIdx.x;
  const int r = tid >> 6;
  const int c = tid & 63;
  const int row = blockIdx.x * 4 + r;
#pragma unroll
  for (int i = 0; i < 4; ++i) {
    *(fv4*)&s_Wn[(i * 256 + tid) * 4] = *(const fv4*)&Wn[(i * 256 + tid) * 4];
    *(fv4*)&s_Ws[(i * 256 + tid) * 4] = *(const fv4*)&Wsn[(i * 256 + tid) * 4];
  }
  s_emb[r][c] = emb_node[row * CH + c];
  __syncthreads();
  float a1 = bn[c], a2 = bsn[c];
#pragma unroll
  for (int k = 0; k < CH; ++k) {
    const float e = s_emb[r][k];
    a1 = fmaf(e, s_Wn[k * CH + c], a1);
    a2 = fmaf(e, s_Ws[k * CH + c], a2);
  }
  node_x[row * CH + c] = a1;
  rsx[row * CH + c] = fmaxf(a2, 0.0f);
}

// ---------------------------------------------------------------------------
// Kernel 2: block = (b,i); wave w owns rows j in [64w, 64w+64), ALL 64 cols.
// Per 16-row tile: 4 coalesced fv4 global loads (16 rows x 256B, no LDS),
// cvt->bf16, 8 MFMAs over 4 independent col-tile accumulators, epilogue with
// prefetched nx/A. Software pipeline: tile t+1 emb loads + tile t nx loads
// issued before tile t compute. Streaming traffic marked nontemporal.
//   edge_x[j,c] = emb[j,:]@We[:,c] + be[c];  edge_out = relu(edge_x)
//   agg[c] += A[j]*edge_x[j,c]*node_x[b,j,c]   (pre-relu edge_x)
// C/D layout: col = 16*ct + (lane&15), row = tile_base + quad*4 + reg  [m89]
// ---------------------------------------------------------------------------
__global__ __launch_bounds__(256) void edge_mfma_kernel(
    const float* __restrict__ A, const float* __restrict__ emb_edge,
    const float* __restrict__ We, const float* __restrict__ be,
    const float* __restrict__ node_x, const float* __restrict__ rsx,
    float* __restrict__ node_out, float* __restrict__ edge_out) {
  const int bi   = blockIdx.x;         // b*N + i
  const int b    = bi >> 8;
  const int tid  = threadIdx.x;
  const int lane = tid & 63;
  const int wave = tid >> 6;           // 0..3 -> j-range [64w, 64w+64)
  const int l15  = lane & 15;
  const int quad = lane >> 4;

  __shared__ float s_A[NN];
  __shared__ float s_agg[CH];

  s_A[tid] = A[(size_t)bi * NN + tid];
  if (tid < CH) s_agg[tid] = 0.0f;

  // B fragments for all 4 col-tiles: We[k, 16ct+l15], k = h*32 + quad*8 + j
  short8 bfrag[4][2];
  float bias[4];
#pragma unroll
  for (int ct = 0; ct < 4; ++ct) {
    const int c = 16 * ct + l15;
#pragma unroll
    for (int h = 0; h < 2; ++h)
#pragma unroll
      for (int j = 0; j < 8; ++j)
        bfrag[ct][h][j] = f2bf(We[(h * 32 + quad * 8 + j) * CH + c]);
    bias[ct] = be[c];
  }

  const float* __restrict__ ee = emb_edge + (size_t)bi * NN * CH;
  float*       __restrict__ eo = edge_out + (size_t)bi * NN * CH;
  const float* __restrict__ nx = node_x + (size_t)b * NN * CH;

  const int jbase = wave * 64;
  __syncthreads();   // s_A / s_agg ready

  // emb load pointer for this lane: row jbase + t*16 + l15, k-offset quad*8
  // (two 16B chunks per k-half: +0/+4 and +32/+36 floats)
  fv4 ld[2][4];
#pragma unroll
  for (int q = 0; q < 4; ++q) {
    const float* p = ee + (size_t)(jbase + l15) * CH + quad * 8 + (q & 1) * 4 + (q >> 1) * 32;
    ld[0][q] = __builtin_nontemporal_load((const fv4*)p);
  }

  float agg[4] = {0.0f, 0.0f, 0.0f, 0.0f};

#pragma unroll
  for (int t = 0; t < 4; ++t) {
    const int pb = t & 1;
    // issue emb loads for tile t+1
    if (t < 3) {
#pragma unroll
      for (int q = 0; q < 4; ++q) {
        const float* p = ee + (size_t)(jbase + (t + 1) * 16 + l15) * CH +
                         quad * 8 + (q & 1) * 4 + (q >> 1) * 32;
        ld[pb ^ 1][q] = __builtin_nontemporal_load((const fv4*)p);
      }
    }
    // issue nx loads for tile t (L2-resident; covered by cvt+MFMA below)
    const int rbase = jbase + t * 16 + quad * 4;
    float nxv[4][4];
#pragma unroll
    for (int ct = 0; ct < 4; ++ct)
#pragma unroll
      for (int r = 0; r < 4; ++r)
        nxv[ct][r] = nx[(rbase + r) * CH + 16 * ct + l15];

    // compute tile t: 4 independent accumulator chains
    const short8 af0 = cvt8(ld[pb][0], ld[pb][1]);
    const short8 af1 = cvt8(ld[pb][2], ld[pb][3]);
    fv4 acc[4];
#pragma unroll
    for (int ct = 0; ct < 4; ++ct) {
      acc[ct] = fv4{0.0f, 0.0f, 0.0f, 0.0f};
      acc[ct] = __builtin_amdgcn_mfma_f32_16x16x32_bf16(af0, bfrag[ct][0], acc[ct], 0, 0, 0);
      acc[ct] = __builtin_amdgcn_mfma_f32_16x16x32_bf16(af1, bfrag[ct][1], acc[ct], 0, 0, 0);
    }

    // epilogue tile t
    const fv4 av = *(const fv4*)&s_A[rbase];   // quad-broadcast, conflict-free
#pragma unroll
    for (int ct = 0; ct < 4; ++ct) {
      const int c = 16 * ct + l15;
#pragma unroll
      for (int r = 0; r < 4; ++r) {
        const float ex = acc[ct][r] + bias[ct];          // pre-relu edge_x
        __builtin_nontemporal_store(fmaxf(ex, 0.0f), eo + (rbase + r) * CH + c);
        agg[ct] = fmaf(av[r] * ex, nxv[ct][r], agg[ct]);
      }
    }
  }

  // reduce quads within wave (same col at lane^16, lane^32), then across waves
#pragma unroll
  for (int ct = 0; ct < 4; ++ct) {
    agg[ct] += __shfl_xor(agg[ct], 16, 64);
    agg[ct] += __shfl_xor(agg[ct], 32, 64);
  }
  if (quad == 0) {
#pragma unroll
    for (int ct = 0; ct < 4; ++ct)
      atomicAdd(&s_agg[16 * ct + l15], agg[ct]);
  }
  __syncthreads();
  if (tid < CH) {
    node_out[(size_t)bi * CH + tid] =
        fmaxf(s_agg[tid], 0.0f) + rsx[(size_t)bi * CH + tid];
  }
}

// ---------------------------------------------------------------------------
extern "C" void kernel_launch(void* const* d_in, const int* in_sizes, int n_in,
                              void* d_out, int out_size, void* d_ws, size_t ws_size,
                              hipStream_t stream) {
  const float* A        = (const float*)d_in[0];  // [8,256,256]
  const float* emb_node = (const float*)d_in[1];  // [8,256,64]
  const float* emb_edge = (const float*)d_in[2];  // [8,256,256,64]
  const float* Wn       = (const float*)d_in[3];  // [64,64]
  const float* bn       = (const float*)d_in[4];  // [64]
  const float* Wsn      = (const float*)d_in[5];  // [64,64]
  const float* bsn      = (const float*)d_in[6];  // [64]
  const float* We       = (const float*)d_in[7];  // [64,64]
  const float* be       = (const float*)d_in[8];  // [64]

  float* node_out = (float*)d_out;                     // [2048,64]
  float* edge_out = (float*)d_out + (size_t)BN * CH;   // [2048,256,64]

  float* node_x = (float*)d_ws;                        // [2048,64] fp32
  float* rsx    = (float*)d_ws + (size_t)BN * CH;      // [2048,64] fp32

  hipLaunchKernelGGL(node_kernel, dim3(BN / 4), dim3(256), 0, stream,
                     emb_node, Wn, bn, Wsn, bsn, node_x, rsx);
  hipLaunchKernelGGL(edge_mfma_kernel, dim3(BN), dim3(256), 0, stream,
                     A, emb_edge, We, be, node_x, rsx, node_out, edge_out);
}

// Round 5
// 268.297 us; speedup vs baseline: 1.0025x; 1.0025x over previous
//
#include <hip/hip_runtime.h>
#include <hip/hip_bf16.h>

// Problem constants (B=8, N=256, DIN=DOUT=EIN=EOUT=64)
#define BN   2048      // B*N
#define NN   256       // N
#define CH   64        // channel dims

typedef __attribute__((ext_vector_type(8))) short short8;   // 8 bf16
typedef __attribute__((ext_vector_type(4))) float fv4;

// fp32 -> bf16 bits, round-to-nearest-even (used for weights only)
static __device__ inline short f2bf(float f) {
  unsigned u = __float_as_uint(f);
  u += 0x7FFF + ((u >> 16) & 1);
  return (short)(u >> 16);
}

// 8x fp32 -> 8x bf16 by truncation: one v_perm_b32 per 2 floats.
// perm(hi,lo,0x07060302): b0=lo.b2 b1=lo.b3 b2=hi.b2 b3=hi.b3
static __device__ inline short8 pk8(fv4 a, fv4 b) {
  union { short8 s; unsigned u[4]; } r;
  r.u[0] = __builtin_amdgcn_perm(__float_as_uint(a[1]), __float_as_uint(a[0]), 0x07060302u);
  r.u[1] = __builtin_amdgcn_perm(__float_as_uint(a[3]), __float_as_uint(a[2]), 0x07060302u);
  r.u[2] = __builtin_amdgcn_perm(__float_as_uint(b[1]), __float_as_uint(b[0]), 0x07060302u);
  r.u[3] = __builtin_amdgcn_perm(__float_as_uint(b[3]), __float_as_uint(b[2]), 0x07060302u);
  return r.s;
}

// ---------------------------------------------------------------------------
// Kernel 1: node_x = emb_node@Wn + bn (fp32), rsx = relu(emb_node@Wsn + bsn).
// ---------------------------------------------------------------------------
__global__ __launch_bounds__(256) void node_kernel(
    const float* __restrict__ emb_node, const float* __restrict__ Wn,
    const float* __restrict__ bn, const float* __restrict__ Wsn,
    const float* __restrict__ bsn, float* __restrict__ node_x,
    float* __restrict__ rsx) {
  __shared__ float s_emb[4][CH];
  __shared__ float s_Wn[CH * CH];
  __shared__ float s_Ws[CH * CH];
  const int tid = threadIdx.x;
  const int r = tid >> 6;
  const int c = tid & 63;
  const int row = blockIdx.x * 4 + r;
#pragma unroll
  for (int i = 0; i < 4; ++i) {
    *(fv4*)&s_Wn[(i * 256 + tid) * 4] = *(const fv4*)&Wn[(i * 256 + tid) * 4];
    *(fv4*)&s_Ws[(i * 256 + tid) * 4] = *(const fv4*)&Wsn[(i * 256 + tid) * 4];
  }
  s_emb[r][c] = emb_node[row * CH + c];
  __syncthreads();
  float a1 = bn[c], a2 = bsn[c];
#pragma unroll
  for (int k = 0; k < CH; ++k) {
    const float e = s_emb[r][k];
    a1 = fmaf(e, s_Wn[k * CH + c], a1);
    a2 = fmaf(e, s_Ws[k * CH + c], a2);
  }
  node_x[row * CH + c] = a1;
  rsx[row * CH + c] = fmaxf(a2, 0.0f);
}

// ---------------------------------------------------------------------------
// Kernel 2: block = (b,i); wave w owns rows j in [64w, 64w+64), ALL 64 cols.
// Per 16-row tile: 4 coalesced fv4 global loads, v_perm truncate->bf16,
// 8 MFMAs over 4 independent col-tile accumulators.
// Pipeline: emb loads 2 tiles deep, nx loads 1 tile deep (ping-pong).
//   edge_x[j,c] = emb[j,:]@We[:,c] + be[c];  edge_out = relu(edge_x)
//   agg[c] += A[j]*edge_x[j,c]*node_x[b,j,c]   (pre-relu edge_x)
// C/D layout: col = 16*ct + (lane&15), row = tile_base + quad*4 + reg  [m89]
// ---------------------------------------------------------------------------
__global__ __launch_bounds__(256) void edge_mfma_kernel(
    const float* __restrict__ A, const float* __restrict__ emb_edge,
    const float* __restrict__ We, const float* __restrict__ be,
    const float* __restrict__ node_x, const float* __restrict__ rsx,
    float* __restrict__ node_out, float* __restrict__ edge_out) {
  const int bi   = blockIdx.x;         // b*N + i
  const int b    = bi >> 8;
  const int tid  = threadIdx.x;
  const int lane = tid & 63;
  const int wave = tid >> 6;           // 0..3 -> j-range [64w, 64w+64)
  const int l15  = lane & 15;
  const int quad = lane >> 4;

  __shared__ float s_A[NN];
  __shared__ float s_agg[CH];

  s_A[tid] = A[(size_t)bi * NN + tid];
  if (tid < CH) s_agg[tid] = 0.0f;

  const float* __restrict__ ee = emb_edge + (size_t)bi * NN * CH;
  float*       __restrict__ eo = edge_out + (size_t)bi * NN * CH;
  const float* __restrict__ nx = node_x + (size_t)b * NN * CH;
  const int jbase = wave * 64;

  // ---- issue emb loads for tiles 0 and 1 FIRST (deepest latency) ----
  fv4 ld[4][4];   // per-tile buffers; loop fully unrolled -> register-renamed
#pragma unroll
  for (int t = 0; t < 2; ++t)
#pragma unroll
    for (int q = 0; q < 4; ++q) {
      const float* p = ee + (size_t)(jbase + t * 16 + l15) * CH +
                       quad * 8 + (q & 1) * 4 + (q >> 1) * 32;
      ld[t][q] = __builtin_nontemporal_load((const fv4*)p);
    }

  // nx prefetch for tile 0 (ping-pong)
  float nxv[2][4][4];
#pragma unroll
  for (int ct = 0; ct < 4; ++ct)
#pragma unroll
    for (int r = 0; r < 4; ++r)
      nxv[0][ct][r] = nx[(jbase + quad * 4 + r) * CH + 16 * ct + l15];

  // B fragments for all 4 col-tiles: We[k, 16ct+l15], k = h*32 + quad*8 + j
  short8 bfrag[4][2];
  float bias[4];
#pragma unroll
  for (int ct = 0; ct < 4; ++ct) {
    const int c = 16 * ct + l15;
#pragma unroll
    for (int h = 0; h < 2; ++h)
#pragma unroll
      for (int j = 0; j < 8; ++j)
        bfrag[ct][h][j] = f2bf(We[(h * 32 + quad * 8 + j) * CH + c]);
    bias[ct] = be[c];
  }

  float agg[4] = {0.0f, 0.0f, 0.0f, 0.0f};
  __syncthreads();   // s_A / s_agg ready

#pragma unroll
  for (int t = 0; t < 4; ++t) {
    // emb loads for tile t+2
    if (t < 2) {
#pragma unroll
      for (int q = 0; q < 4; ++q) {
        const float* p = ee + (size_t)(jbase + (t + 2) * 16 + l15) * CH +
                         quad * 8 + (q & 1) * 4 + (q >> 1) * 32;
        ld[t + 2][q] = __builtin_nontemporal_load((const fv4*)p);
      }
    }
    // nx loads for tile t+1
    if (t < 3) {
      const int rb1 = jbase + (t + 1) * 16 + quad * 4;
#pragma unroll
      for (int ct = 0; ct < 4; ++ct)
#pragma unroll
        for (int r = 0; r < 4; ++r)
          nxv[(t + 1) & 1][ct][r] = nx[(rb1 + r) * CH + 16 * ct + l15];
    }

    // compute tile t
    const short8 af0 = pk8(ld[t][0], ld[t][1]);
    const short8 af1 = pk8(ld[t][2], ld[t][3]);
    fv4 acc[4];
#pragma unroll
    for (int ct = 0; ct < 4; ++ct) {
      acc[ct] = fv4{0.0f, 0.0f, 0.0f, 0.0f};
      acc[ct] = __builtin_amdgcn_mfma_f32_16x16x32_bf16(af0, bfrag[ct][0], acc[ct], 0, 0, 0);
      acc[ct] = __builtin_amdgcn_mfma_f32_16x16x32_bf16(af1, bfrag[ct][1], acc[ct], 0, 0, 0);
    }

    // epilogue tile t
    const int rbase = jbase + t * 16 + quad * 4;
    const fv4 av = *(const fv4*)&s_A[rbase];   // quad-broadcast, conflict-free
#pragma unroll
    for (int ct = 0; ct < 4; ++ct) {
      const int c = 16 * ct + l15;
#pragma unroll
      for (int r = 0; r < 4; ++r) {
        const float ex = acc[ct][r] + bias[ct];          // pre-relu edge_x
        __builtin_nontemporal_store(fmaxf(ex, 0.0f), eo + (rbase + r) * CH + c);
        agg[ct] = fmaf(av[r] * ex, nxv[t & 1][ct][r], agg[ct]);
      }
    }
  }

  // reduce quads within wave (same col at lane^16, lane^32), then across waves
#pragma unroll
  for (int ct = 0; ct < 4; ++ct) {
    agg[ct] += __shfl_xor(agg[ct], 16, 64);
    agg[ct] += __shfl_xor(agg[ct], 32, 64);
  }
  if (quad == 0) {
#pragma unroll
    for (int ct = 0; ct < 4; ++ct)
      atomicAdd(&s_agg[16 * ct + l15], agg[ct]);
  }
  __syncthreads();
  if (tid < CH) {
    node_out[(size_t)bi * CH + tid] =
        fmaxf(s_agg[tid], 0.0f) + rsx[(size_t)bi * CH + tid];
  }
}

// ---------------------------------------------------------------------------
extern "C" void kernel_launch(void* const* d_in, const int* in_sizes, int n_in,
                              void* d_out, int out_size, void* d_ws, size_t ws_size,
                              hipStream_t stream) {
  const float* A        = (const float*)d_in[0];  // [8,256,256]
  const float* emb_node = (const float*)d_in[1];  // [8,256,64]
  const float* emb_edge = (const float*)d_in[2];  // [8,256,256,64]
  const float* Wn       = (const float*)d_in[3];  // [64,64]
  const float* bn       = (const float*)d_in[4];  // [64]
  const float* Wsn      = (const float*)d_in[5];  // [64,64]
  const float* bsn      = (const float*)d_in[6];  // [64]
  const float* We       = (const float*)d_in[7];  // [64,64]
  const float* be       = (const float*)d_in[8];  // [64]

  float* node_out = (float*)d_out;                     // [2048,64]
  float* edge_out = (float*)d_out + (size_t)BN * CH;   // [2048,256,64]

  float* node_x = (float*)d_ws;                        // [2048,64] fp32
  float* rsx    = (float*)d_ws + (size_t)BN * CH;      // [2048,64] fp32

  hipLaunchKernelGGL(node_kernel, dim3(BN / 4), dim3(256), 0, stream,
                     emb_node, Wn, bn, Wsn, bsn, node_x, rsx);
  hipLaunchKernelGGL(edge_mfma_kernel, dim3(BN), dim3(256), 0, stream,
                     A, emb_edge, We, be, node_x, rsx, node_out, edge_out);
}